// Round 5
// baseline (143.338 us; speedup 1.0000x reference)
//
#include <hip/hip_runtime.h>

// Static shapes: B=16, T=512, D=384 (=96 float4), F=max_len=4096.
#define BB    16
#define TT    512
#define FF    4096
#define DD4   96                 // float4 per row
#define NTHR  256
#define FPB   64                 // frames per block
#define CHUNKS (FF / FPB)        // 64 chunks per batch
#define NBLK  (BB * CHUNKS)      // 1024 blocks
#define PPB   (FPB * DD4)        // 6144 float4 per block chunk
#define NXCD  8

typedef float f4 __attribute__((ext_vector_type(4)));

// R5 = R4 kernel, launched TWICE (idempotent). Calibration round:
// dur_us(R5) - dur_us(R4), clock-normalized by the fill dispatches,
// directly measures one kernel invocation's duration -- the quantity the
// top-5 counter rows (all harness fills) have hidden for four rounds.
__global__ __launch_bounds__(NTHR) void lenreg_kernel(
    const f4* __restrict__ x, const int* __restrict__ dur,
    f4* __restrict__ out) {

    int bid = blockIdx.x;
    // bijective XCD swizzle (1024 % 8 == 0)
    bid = (bid & (NXCD - 1)) * (NBLK / NXCD) + (bid >> 3);

    const int b     = bid >> 6;          // bid / CHUNKS
    const int chunk = bid & (CHUNKS - 1);
    const int t     = threadIdx.x;
    const int lane  = t & 63;
    const int wid   = t >> 6;

    __shared__ int s_cum[TT];
    __shared__ int s_ws[NTHR / 64];
    __shared__ int s_idx[FPB];

    // ---- scan: each thread owns durations 2t, 2t+1 ----
    const int2 dd = ((const int2*)(dur + b * TT))[t];
    int v = dd.x + dd.y;
#pragma unroll
    for (int off = 1; off < 64; off <<= 1) {
        int u = __shfl_up(v, off, 64);
        if (lane >= off) v += u;
    }
    if (lane == 63) s_ws[wid] = v;
    __syncthreads();
    int base = 0;
#pragma unroll
    for (int w = 0; w < NTHR / 64 - 1; ++w)
        if (w < wid) base += s_ws[w];
    const int c1 = base + v;             // inclusive cum[2t+1]
    s_cum[2 * t]     = c1 - dd.y;        // inclusive cum[2t]
    s_cum[2 * t + 1] = c1;
    __syncthreads();

    const int total = s_cum[TT - 1];     // <= 512*7 = 3584 < 4096
    const int fbase = chunk * FPB;

    // ---- one search per frame of this chunk (wave 0 does all 64) ----
    if (t < FPB) {
        const int f = fbase + t;
        int idx = 0;
#pragma unroll
        for (int step = 256; step > 0; step >>= 1)
            if (idx + step <= TT && s_cum[idx + step - 1] <= f) idx += step;
        s_idx[t] = idx < TT - 1 ? idx : TT - 1;   // reference's clamp
    }
    __syncthreads();

    // ---- byte-linear store phase ----
    const f4* xb = x + (size_t)b * TT * DD4;
    f4* ob = out + (size_t)(b * FF + fbase) * DD4;
#pragma unroll
    for (int k = 0; k < PPB / NTHR; ++k) {       // 24 iterations
        const int p = t + NTHR * k;              // 0..6143
        const int f = p / DD4;                   // magic-div by 96
        const int c = p - f * DD4;
        f4 val = {0.f, 0.f, 0.f, 0.f};
        if (fbase + f < total) val = xb[s_idx[f] * DD4 + c];
        ob[p] = val;
    }
}

extern "C" void kernel_launch(void* const* d_in, const int* in_sizes, int n_in,
                              void* d_out, int out_size, void* d_ws, size_t ws_size,
                              hipStream_t stream) {
    const float* x = (const float*)d_in[0];
    const int* dur = (const int*)d_in[1];   // int32 on device
    (void)d_ws; (void)ws_size;

    // Launched twice on purpose (idempotent): the dur_us delta vs R4
    // measures one kernel invocation. See round journal.
    lenreg_kernel<<<NBLK, NTHR, 0, stream>>>((const f4*)x, dur, (f4*)d_out);
    lenreg_kernel<<<NBLK, NTHR, 0, stream>>>((const f4*)x, dur, (f4*)d_out);
}

// Round 6
// 125.208 us; speedup vs baseline: 1.1448x; 1.1448x over previous
//
#include <hip/hip_runtime.h>

// Static shapes: B=16, T=512, D=384 (=96 float4), F=max_len=4096.
#define BB    16
#define TT    512
#define FF    4096
#define DD4   96                 // float4 per row
#define NTHR  256
#define FPB   64                 // frames per block
#define CHUNKS (FF / FPB)        // 64 chunks per batch
#define NBLK  (BB * CHUNKS)      // 1024 blocks
#define PPB   (FPB * DD4)        // 6144 float4 per block chunk
#define NXCD  8

typedef float f4 __attribute__((ext_vector_type(4)));

// Final form (R4 kernel, single launch; R5's duplicate calibration launch
// removed). Measured via the R4/R5 double-launch delta: ~18 us per
// invocation = mandatory HBM traffic (113 MB) at ~6.3 TB/s -- the same
// achievable ceiling the harness's own 384 MiB fill hits (80-83% of peak).
//  1. shfl+LDS scan of durations -> cum[512] in LDS
//  2. one branchless binary search per frame (searchsorted side="right"
//     + clamp, exact reference semantics incl. zero-duration phonemes)
//  3. byte-linear store phase: thread t writes float4 p = t + 256k of the
//     block's contiguous 96 KB output chunk (wave-linear 1024 B stores);
//     frame = p/96 via magic-div, phoneme idx broadcast from LDS.
__global__ __launch_bounds__(NTHR) void lenreg_kernel(
    const f4* __restrict__ x, const int* __restrict__ dur,
    f4* __restrict__ out) {

    int bid = blockIdx.x;
    // bijective XCD swizzle (1024 % 8 == 0)
    bid = (bid & (NXCD - 1)) * (NBLK / NXCD) + (bid >> 3);

    const int b     = bid >> 6;          // bid / CHUNKS
    const int chunk = bid & (CHUNKS - 1);
    const int t     = threadIdx.x;
    const int lane  = t & 63;
    const int wid   = t >> 6;

    __shared__ int s_cum[TT];
    __shared__ int s_ws[NTHR / 64];
    __shared__ int s_idx[FPB];

    // ---- scan: each thread owns durations 2t, 2t+1 ----
    const int2 dd = ((const int2*)(dur + b * TT))[t];
    int v = dd.x + dd.y;
#pragma unroll
    for (int off = 1; off < 64; off <<= 1) {
        int u = __shfl_up(v, off, 64);
        if (lane >= off) v += u;
    }
    if (lane == 63) s_ws[wid] = v;
    __syncthreads();
    int base = 0;
#pragma unroll
    for (int w = 0; w < NTHR / 64 - 1; ++w)
        if (w < wid) base += s_ws[w];
    const int c1 = base + v;             // inclusive cum[2t+1]
    s_cum[2 * t]     = c1 - dd.y;        // inclusive cum[2t]
    s_cum[2 * t + 1] = c1;
    __syncthreads();

    const int total = s_cum[TT - 1];     // <= 512*7 = 3584 < 4096
    const int fbase = chunk * FPB;

    // ---- one search per frame of this chunk (wave 0 does all 64) ----
    if (t < FPB) {
        const int f = fbase + t;
        int idx = 0;
#pragma unroll
        for (int step = 256; step > 0; step >>= 1)
            if (idx + step <= TT && s_cum[idx + step - 1] <= f) idx += step;
        s_idx[t] = idx < TT - 1 ? idx : TT - 1;   // reference's clamp
    }
    __syncthreads();

    // ---- byte-linear store phase ----
    const f4* xb = x + (size_t)b * TT * DD4;
    f4* ob = out + (size_t)(b * FF + fbase) * DD4;
#pragma unroll
    for (int k = 0; k < PPB / NTHR; ++k) {       // 24 iterations
        const int p = t + NTHR * k;              // 0..6143
        const int f = p / DD4;                   // magic-div by 96
        const int c = p - f * DD4;
        f4 val = {0.f, 0.f, 0.f, 0.f};
        if (fbase + f < total) val = xb[s_idx[f] * DD4 + c];
        ob[p] = val;
    }
}

extern "C" void kernel_launch(void* const* d_in, const int* in_sizes, int n_in,
                              void* d_out, int out_size, void* d_ws, size_t ws_size,
                              hipStream_t stream) {
    const float* x = (const float*)d_in[0];
    const int* dur = (const int*)d_in[1];   // int32 on device
    (void)d_ws; (void)ws_size;

    lenreg_kernel<<<NBLK, NTHR, 0, stream>>>(
        (const f4*)x, dur, (f4*)d_out);
}